// Round 1
// baseline (108.428 us; speedup 1.0000x reference)
//
#include <hip/hip_runtime.h>

// ECT layer: ect[b,s,t] = sum_{n in graph b} sigmoid(500*(lin[s] - x[n,:]@v[:,t]))
// N=50000, F=3, T=64, S=64, B=128. Compute-bound (205M sigmoids), inputs L2-resident.
//
// Layout: lane = t (64 thetas == wave width), 4 waves/block each own a 16-wide
// s-strip in registers. Grid = B * SPLIT blocks; each block handles a contiguous
// node chunk of one graph (batch is sorted -> binary search the range), then
// atomicAdds its 16 partial sums per thread into out.

#define THREADS 256
#define SPLIT   8

__global__ __launch_bounds__(THREADS) void ect_dense_kernel(
    const float* __restrict__ x,     // (N,3)
    const float* __restrict__ v,     // (3,64)
    const float* __restrict__ lin,   // (64)
    const int*  __restrict__ batch,  // (N) sorted ascending in [0,B)
    float* __restrict__ out,         // (B,64,64), pre-zeroed
    int N, int B)
{
    const float KSH = 721.3475204444817f;  // 500 / ln(2)

    const int b     = blockIdx.x / SPLIT;
    const int split = blockIdx.x - b * SPLIT;

    // [start,end) of graph b in sorted batch (uniform across block -> scalar-ish)
    int lo = 0, hi = N;
    while (lo < hi) { int m = (lo + hi) >> 1; if (batch[m] < b) lo = m + 1; else hi = m; }
    const int start = lo;
    hi = N;
    while (lo < hi) { int m = (lo + hi) >> 1; if (batch[m] <= b) lo = m + 1; else hi = m; }
    const int end = lo;

    const int cnt = end - start;
    const int n0 = start + (cnt * split) / SPLIT;
    const int n1 = start + (cnt * (split + 1)) / SPLIT;

    const int t = threadIdx.x & 63;   // theta index == lane
    const int w = threadIdx.x >> 6;   // wave id 0..3 -> s-strip

    // premultiplied direction column: a = KSH * (x . v[:,t])
    const float kv0 = KSH * v[t];
    const float kv1 = KSH * v[64 + t];
    const float kv2 = KSH * v[128 + t];

    float kl[16], acc[16];
#pragma unroll
    for (int i = 0; i < 16; ++i) {
        kl[i]  = KSH * lin[w * 16 + i];
        acc[i] = 0.0f;
    }

    for (int n = n0; n < n1; ++n) {
        const float x0 = x[n * 3 + 0];
        const float x1 = x[n * 3 + 1];
        const float x2 = x[n * 3 + 2];
        const float a  = x0 * kv0 + x1 * kv1 + x2 * kv2;  // KSH * nh[n][t]
#pragma unroll
        for (int i = 0; i < 16; ++i) {
            // sigmoid(500*(lin-nh)) = 1 / (1 + exp2(KSH*nh - KSH*lin))
            const float p = __builtin_amdgcn_exp2f(a - kl[i]);
            acc[i] += __builtin_amdgcn_rcpf(1.0f + p);
        }
    }

    float* ob = out + (size_t)b * 64 * 64;
#pragma unroll
    for (int i = 0; i < 16; ++i) {
        atomicAdd(&ob[(w * 16 + i) * 64 + t], acc[i]);
    }
}

extern "C" void kernel_launch(void* const* d_in, const int* in_sizes, int n_in,
                              void* d_out, int out_size, void* d_ws, size_t ws_size,
                              hipStream_t stream)
{
    const float* x     = (const float*)d_in[0];
    const float* v     = (const float*)d_in[1];
    const float* lin   = (const float*)d_in[2];
    const int*   batch = (const int*)d_in[3];
    float*       out   = (float*)d_out;

    const int N = in_sizes[0] / 3;          // 50000
    const int S = in_sizes[2];              // 64
    const int B = out_size / (S * 64);      // 128

    // harness poisons d_out with 0xAA before every timed replay
    hipMemsetAsync(d_out, 0, (size_t)out_size * sizeof(float), stream);

    dim3 grid(B * SPLIT);
    dim3 block(THREADS);
    ect_dense_kernel<<<grid, block, 0, stream>>>(x, v, lin, batch, out, N, B);
}